// Round 12
// baseline (211.868 us; speedup 1.0000x reference)
//
#include <hip/hip_runtime.h>

#define H_ 56
#define W_ 56
#define HW_ 3136
#define CIN_ 256
#define COUT_ 256

typedef __attribute__((ext_vector_type(8))) short short8;
typedef __attribute__((ext_vector_type(4))) float f32x4;

// Pre-swizzled bf16 weights, written by prep_weights each launch (idempotent).
// Layout: [bm][kt][e], e = m*32 + col, content = bf16(W[bm*128+m][kt*32 + (col ^ swz32(m))])
__device__ unsigned short g_wbf[COUT_ * CIN_];

__device__ __forceinline__ int swz32(int n) { return ((n ^ (n >> 3)) & 3) << 3; }

__device__ __forceinline__ unsigned short f2bf(float f) {
  union { float f; unsigned int i; } v; v.f = f;
  unsigned int b = v.i + (0x7fffu + ((v.i >> 16) & 1u));  // RNE
  return (unsigned short)(b >> 16);
}

__device__ __forceinline__ void gload_lds16(const unsigned short* g, unsigned short* l) {
  __builtin_amdgcn_global_load_lds(
      (const __attribute__((address_space(1))) unsigned int*)g,
      (__attribute__((address_space(3))) unsigned int*)l, 16, 0, 0);
}

__device__ __forceinline__ void shift_decode(int c, int& dx, int& dy) {
  if (c < 102)      { dy = 0; dx = (c < 51) ? 0 : 1; }
  else if (c < 153) { dx = -1; dy = 0; }
  else if (c < 204) { dx = 0;  dy = 1; }
  else              { dx = 0;  dy = -1; }
}

__global__ __launch_bounds__(256)
void prep_weights(const float* __restrict__ wgt) {
  int idx  = blockIdx.x * 256 + threadIdx.x;   // 0..65535
  int tile = idx >> 12;                        // bm*8 + kt
  int bm = tile >> 3, kt = tile & 7;
  int e   = idx & 4095;
  int m   = e >> 5, col = e & 31;
  int o   = bm * 128 + m;
  int k   = kt * 32 + (col ^ swz32(m));
  g_wbf[idx] = f2bf(wgt[o * CIN_ + k]);
}

// Load next x slice into registers (shift applied later at LDS-write time).
__device__ __forceinline__ void load_x(const float* __restrict__ x, size_t xb,
                                       int hh, int w0, int c,
                                       float4& p0, float4& p1, float& pe) {
  int dx, dy; shift_decode(c, dx, dy);
  int h2 = hh - dy;
  p0 = make_float4(0.f, 0.f, 0.f, 0.f);
  p1 = make_float4(0.f, 0.f, 0.f, 0.f);
  pe = 0.f;
  if ((unsigned)h2 < (unsigned)H_) {
    const float* row = x + xb + (size_t)c * HW_ + h2 * W_;
    p0 = *(const float4*)(row + w0);
    p1 = *(const float4*)(row + w0 + 4);
    if (dx == 1)       { if (w0 > 0)      pe = row[w0 - 1]; }
    else if (dx == -1) { if (w0 + 8 < W_) pe = row[w0 + 8]; }
  }
}

// Apply the W-shift in registers and scatter bf16 into the (transposed) B tile.
__device__ __forceinline__ void write_b(unsigned short* __restrict__ B,
                                        int nloc0, int krow, int c,
                                        const float4& p0, const float4& p1, float pe) {
  int dx, dy; shift_decode(c, dx, dy);
  float s[8] = {p0.x, p0.y, p0.z, p0.w, p1.x, p1.y, p1.z, p1.w};
  float vals[8];
  if (dx == 0) {
    #pragma unroll
    for (int i = 0; i < 8; ++i) vals[i] = s[i];
  } else if (dx == 1) {          // y[w] = x[w-1]
    #pragma unroll
    for (int i = 7; i >= 1; --i) vals[i] = s[i - 1];
    vals[0] = pe;
  } else {                       // dx == -1: y[w] = x[w+1]
    #pragma unroll
    for (int i = 0; i < 7; ++i) vals[i] = s[i + 1];
    vals[7] = pe;
  }
  #pragma unroll
  for (int i = 0; i < 8; ++i) {
    int nl = nloc0 + i;
    B[nl * 32 + (krow ^ swz32(nl))] = f2bf(vals[i]);
  }
}

__global__ __launch_bounds__(256, 4)
void shiftconv_gemm(const float* __restrict__ x,
                    const float* __restrict__ gamma,
                    const float* __restrict__ beta,
                    const float* __restrict__ rmean,
                    const float* __restrict__ rvar,
                    float* __restrict__ out)
{
  // ONLY change vs R11 (77.7 us): 2-deep x prefetch + raw barriers (no vmcnt
  // drain in-loop) + A triple-buffer so the staging DMA never targets a live
  // read buffer. x(t+2) issues at tile t, consumed at end of tile t+1 ->
  // load latency hidden across a full tile instead of one MFMA phase.
  __shared__ unsigned short Alds[3][128 * 32];   // 3 x 8 KB
  __shared__ unsigned short Blds[2][64 * 32];    // 2 x 4 KB
  __shared__ float bnp[256];                     // interleaved (inv, add)

  const int t = threadIdx.x;
  // XCD-bijective swizzle (verified: FETCH 137.7 -> 51.0 MB on this base).
  const int orig = blockIdx.x;
  const int wgid = (orig & 7) * 392 + (orig >> 3);
  const int bm   = wgid & 1;     // 2 m-tiles of 128
  const int bn   = wgid >> 1;    // 1568 n-tiles of 64

  const int lane = t & 63;
  const int wv   = t >> 6;
  const int wm   = wv >> 1;      // wave m-half (64 rows)
  const int wn   = wv & 1;       // wave n-half (32 cols)
  const int quad = lane >> 4;
  const int l15  = lane & 15;

  if (t < 128) {
    int o = bm * 128 + t;
    float inv = gamma[o] * rsqrtf(rvar[o] + 1e-5f);
    bnp[2 * t]     = inv;
    bnp[2 * t + 1] = beta[o] - rmean[o] * inv;
  }

  // ---- B staging decode (constant across K loop): 8 n x 1 k per thread ----
  const int chunk  = t & 7;           // 8 chunks of 8 n
  const int krow   = t >> 3;          // 0..31 = k within tile
  const int nloc0  = chunk * 8;
  const int nglob0 = bn * 64 + nloc0;
  const int bidx   = nglob0 / HW_;
  const int rem    = nglob0 - bidx * HW_;
  const int hh     = rem / W_;
  const int w0     = rem - hh * W_;   // multiple of 8
  const size_t xb  = (size_t)bidx * CIN_ * HW_;

  // ---- A staging source: pre-swizzled bf16 weights ----
  const unsigned short* wsrc = g_wbf + bm * (8 * 4096) + t * 8;

  f32x4 acc[4][2];
  #pragma unroll
  for (int i = 0; i < 4; ++i)
    #pragma unroll
    for (int j = 0; j < 2; ++j)
      acc[i][j] = (f32x4){0.f, 0.f, 0.f, 0.f};

  // Two NAMED x register sets (sA: even-issued, sB: odd-issued) -- static
  // indexing only (rule #20 / R3 spill lesson).
  float4 pa0, pa1; float pea;
  float4 pb0, pb1; float peb;

  const int kb = quad * 8;

  // ---- prologue: A0, A1 staged; B0 written; x(1) in flight ----
  gload_lds16(wsrc,        &Alds[0][wv * 512]);
  gload_lds16(wsrc + 2048, &Alds[0][wv * 512 + 2048]);
  gload_lds16(wsrc + 4096, &Alds[1][wv * 512]);
  gload_lds16(wsrc + 6144, &Alds[1][wv * 512 + 2048]);
  __builtin_amdgcn_sched_barrier(0);
  load_x(x, xb, hh, w0, krow, pa0, pa1, pea);
  write_b(&Blds[0][0], nloc0, krow, krow, pa0, pa1, pea);
  load_x(x, xb, hh, w0, 32 + krow, pb0, pb1, peb);
  __syncthreads();   // full drain once (prologue only)

  // ---- main loop: 4 pairs of tiles; lgkmcnt(0)-only barriers ----
  for (int kt2 = 0; kt2 < 4; ++kt2) {
    const int te     = 2 * kt2;
    const int aCur   = te % 3;         // A buf read this tile
    const int aNext  = (te + 1) % 3;   // A buf read next tile
    const int aStage = (te + 2) % 3;   // A buf being DMA'd (not read this pair)

    // ======== even tile te: read A[aCur], B[0] ========
    if (kt2 < 3) {
      const unsigned short* g = wsrc + (te + 2) * 4096;
      gload_lds16(g,        &Alds[aStage][wv * 512]);
      gload_lds16(g + 2048, &Alds[aStage][wv * 512 + 2048]);
      __builtin_amdgcn_sched_barrier(0);   // pin: A-gloads issue before x-loads
      load_x(x, xb, hh, w0, (te + 2) * 32 + krow, pa0, pa1, pea);
    }
    {
      short8 af[4], bfr[2];
      #pragma unroll
      for (int f = 0; f < 4; ++f) {
        int ml = wm * 64 + f * 16 + l15;
        af[f] = *(const short8*)(&Alds[aCur][ml * 32 + (kb ^ swz32(ml))]);
      }
      #pragma unroll
      for (int g2 = 0; g2 < 2; ++g2) {
        int nl2 = wn * 32 + g2 * 16 + l15;
        bfr[g2] = *(const short8*)(&Blds[0][nl2 * 32 + (kb ^ swz32(nl2))]);
      }
      #pragma unroll
      for (int mf = 0; mf < 4; ++mf)
        #pragma unroll
        for (int nf = 0; nf < 2; ++nf)
          acc[mf][nf] = __builtin_amdgcn_mfma_f32_16x16x32_bf16(
              af[mf], bfr[nf], acc[mf][nf], 0, 0, 0);
    }
    write_b(&Blds[1][0], nloc0, krow, (te + 1) * 32 + krow, pb0, pb1, peb);
    asm volatile("s_waitcnt lgkmcnt(0)" ::: "memory");
    __builtin_amdgcn_s_barrier();
    __builtin_amdgcn_sched_barrier(0);

    // ======== odd tile te+1: read A[aNext], B[1] ========
    if (kt2 < 3) {
      const unsigned short* g = wsrc + (te + 3) * 4096;
      gload_lds16(g,        &Alds[aCur][wv * 512]);        // (te+3)%3 == aCur
      gload_lds16(g + 2048, &Alds[aCur][wv * 512 + 2048]);
      __builtin_amdgcn_sched_barrier(0);
      load_x(x, xb, hh, w0, (te + 3) * 32 + krow, pb0, pb1, peb);
    }
    {
      short8 af[4], bfr[2];
      #pragma unroll
      for (int f = 0; f < 4; ++f) {
        int ml = wm * 64 + f * 16 + l15;
        af[f] = *(const short8*)(&Alds[aNext][ml * 32 + (kb ^ swz32(ml))]);
      }
      #pragma unroll
      for (int g2 = 0; g2 < 2; ++g2) {
        int nl2 = wn * 32 + g2 * 16 + l15;
        bfr[g2] = *(const short8*)(&Blds[1][nl2 * 32 + (kb ^ swz32(nl2))]);
      }
      #pragma unroll
      for (int mf = 0; mf < 4; ++mf)
        #pragma unroll
        for (int nf = 0; nf < 2; ++nf)
          acc[mf][nf] = __builtin_amdgcn_mfma_f32_16x16x32_bf16(
              af[mf], bfr[nf], acc[mf][nf], 0, 0, 0);
    }
    if (kt2 < 3) {
      write_b(&Blds[0][0], nloc0, krow, (te + 2) * 32 + krow, pa0, pa1, pea);
      asm volatile("s_waitcnt lgkmcnt(0)" ::: "memory");
      __builtin_amdgcn_s_barrier();
      __builtin_amdgcn_sched_barrier(0);
    }
  }

  // ---- epilogue: BN + ReLU + fp32 store ----
  size_t nbase[2];
  #pragma unroll
  for (int nf = 0; nf < 2; ++nf) {
    int ng  = bn * 64 + wn * 32 + nf * 16 + l15;
    int b2  = ng / HW_;
    int hw2 = ng - b2 * HW_;
    nbase[nf] = (size_t)b2 * COUT_ * HW_ + hw2;
  }
  #pragma unroll
  for (int mf = 0; mf < 4; ++mf) {
    int mloc = wm * 64 + mf * 16 + quad * 4;   // local o for reg r=0
    float inv[4], add[4];
    #pragma unroll
    for (int r = 0; r < 4; ++r) {
      inv[r] = bnp[2 * (mloc + r)];
      add[r] = bnp[2 * (mloc + r) + 1];
    }
    size_t obase = (size_t)(bm * 128 + mloc) * HW_;
    #pragma unroll
    for (int nf = 0; nf < 2; ++nf) {
      #pragma unroll
      for (int r = 0; r < 4; ++r) {
        float v = fmaf(acc[mf][nf][r], inv[r], add[r]);
        out[nbase[nf] + obase + (size_t)r * HW_] = fmaxf(v, 0.0f);
      }
    }
  }
}

extern "C" void kernel_launch(void* const* d_in, const int* in_sizes, int n_in,
                              void* d_out, int out_size, void* d_ws, size_t ws_size,
                              hipStream_t stream) {
  const float* x     = (const float*)d_in[0];
  const float* wgt   = (const float*)d_in[1];
  const float* gamma = (const float*)d_in[2];
  const float* beta  = (const float*)d_in[3];
  const float* rmean = (const float*)d_in[4];
  const float* rvar  = (const float*)d_in[5];
  float* out = (float*)d_out;

  prep_weights<<<dim3(256), dim3(256), 0, stream>>>(wgt);
  shiftconv_gemm<<<dim3(3136), dim3(256), 0, stream>>>(x, gamma, beta, rmean, rvar, out);
}

// Round 13
// 210.682 us; speedup vs baseline: 1.0056x; 1.0056x over previous
//
#include <hip/hip_runtime.h>

#define H_ 56
#define W_ 56
#define HW_ 3136
#define CIN_ 256
#define COUT_ 256

typedef __attribute__((ext_vector_type(8))) short short8;
typedef __attribute__((ext_vector_type(4))) float f32x4;

// Fragment-ordered bf16 weights (B-operand layout), written by prep_weights.
// idx = (((bm*8+ks)*8+obg)*64+lane)*8+j holds
//   W[bm*128 + obg*16 + (lane&15)][ks*32 + j*4 + (lane>>4)]
// Same k-permutation (c = ks*32 + 4j + quad) on both operands as R10 (verified
// correct): it makes each unrolled x-gather's shift-region compile-time.
__device__ unsigned short g_wbf[COUT_ * CIN_];

__device__ __forceinline__ unsigned short f2bf(float f) {
  union { float f; unsigned int i; } v; v.f = f;
  unsigned int b = v.i + (0x7fffu + ((v.i >> 16) & 1u));  // RNE
  return (unsigned short)(b >> 16);
}

__device__ __forceinline__ void gload_lds16(const unsigned short* g, unsigned short* l) {
  __builtin_amdgcn_global_load_lds(
      (const __attribute__((address_space(1))) unsigned int*)g,
      (__attribute__((address_space(3))) unsigned int*)l, 16, 0, 0);
}

__global__ __launch_bounds__(256)
void prep_weights(const float* __restrict__ wgt) {
  int idx  = blockIdx.x * 256 + threadIdx.x;   // 0..65535
  int j    = idx & 7;
  int lane = (idx >> 3) & 63;
  int obg  = (idx >> 9) & 7;
  int ks   = (idx >> 12) & 7;
  int bm   = idx >> 15;
  int o = bm * 128 + obg * 16 + (lane & 15);
  int k = ks * 32 + j * 4 + (lane >> 4);
  g_wbf[idx] = f2bf(wgt[o * CIN_ + k]);
}

__global__ __launch_bounds__(512, 4)
void shiftconv_gemm(const float* __restrict__ x,
                    const float* __restrict__ gamma,
                    const float* __restrict__ beta,
                    const float* __restrict__ rmean,
                    const float* __restrict__ rvar,
                    float* __restrict__ out)
{
  // W-half resident in LDS for the whole kernel (staged once, frag-ordered:
  // each (ks,obg) fragment is a lane-contiguous 1KB region -> conflict-free
  // ds_read_b128). Reused as the epilogue transpose buffer after a barrier.
  __shared__ unsigned short Wlds[128 * 256];   // 64 KB
  __shared__ float bnp[256];                   // interleaved (inv, add)

  const int t = threadIdx.x;
  // XCD-bijective swizzle (nwg = 1568 = 8*196); bm-pairs (same x chunk)
  // adjacent on the same XCD (verified lever: FETCH 137.7 -> 51 MB).
  const int orig = blockIdx.x;
  const int wgid = (orig & 7) * 196 + (orig >> 3);
  const int bm    = wgid & 1;      // 2 o-halves of 128
  const int chunk = wgid >> 1;     // 784 n-chunks of 128

  const int lane = t & 63;
  const int wv   = t >> 6;         // 8 waves
  const int wo   = wv >> 2;        // o-half within 128 (64)
  const int wn   = wv & 3;         // n-quarter within 128 (32)
  const int quad = lane >> 4;
  const int l15  = lane & 15;

  if (t < 128) {
    int o = bm * 128 + t;
    float inv = gamma[o] * rsqrtf(rvar[o] + 1e-5f);
    bnp[2 * t]     = inv;
    bnp[2 * t + 1] = beta[o] - rmean[o] * inv;
  }

  // ---- stage W-half (64 KB) once: 512 thr x 8 x 16B, linear ----
  {
    const unsigned short* g = g_wbf + bm * 32768 + t * 8;
    unsigned short* l = &Wlds[t * 8];
    #pragma unroll
    for (int p = 0; p < 8; ++p)
      gload_lds16(g + p * 4096, l + p * 4096);
  }

  // ---- per-lane n decode (chunks may straddle image boundaries) ----
  const int ng0 = chunk * 128 + wn * 32 + l15;   // a=0
  const int ng1 = ng0 + 16;                      // a=1
  const int bi0 = ng0 / HW_, rn0 = ng0 - bi0 * HW_;
  const int bi1 = ng1 / HW_, rn1 = ng1 - bi1 * HW_;
  const int hh0 = rn0 / W_,  ww0 = rn0 - hh0 * W_;
  const int hh1 = rn1 / W_,  ww1 = rn1 - hh1 * W_;
  const unsigned int eb0 = (unsigned int)(bi0 * CIN_ * HW_ + rn0 + quad * HW_);
  const unsigned int eb1 = (unsigned int)(bi1 * CIN_ * HW_ + rn1 + quad * HW_);
  const bool v0L = (ww0 >= 1),      v1L = (ww1 >= 1);
  const bool v0R = (ww0 <= W_ - 2), v1R = (ww1 <= W_ - 2);
  const bool v0U = (hh0 >= 1),      v1U = (hh1 >= 1);
  const bool v0D = (hh0 <= H_ - 2), v1D = (hh1 <= H_ - 2);
  // Clamped byte offsets (invalid -> unshifted in-bounds addr, value zeroed).
  unsigned int vo0[5], vo1[5];
  vo0[0] = eb0 * 4;                             vo1[0] = eb1 * 4;
  vo0[1] = (v0L ? eb0 - 1   : eb0) * 4;         vo1[1] = (v1L ? eb1 - 1   : eb1) * 4;
  vo0[2] = (v0R ? eb0 + 1   : eb0) * 4;         vo1[2] = (v1R ? eb1 + 1   : eb1) * 4;
  vo0[3] = (v0U ? eb0 - W_  : eb0) * 4;         vo1[3] = (v1U ? eb1 - W_  : eb1) * 4;
  vo0[4] = (v0D ? eb0 + W_  : eb0) * 4;         vo1[4] = (v1D ? eb1 + W_  : eb1) * 4;
  float fm0[5], fm1[5];
  fm0[0] = 1.f;               fm1[0] = 1.f;
  fm0[1] = v0L ? 1.f : 0.f;   fm1[1] = v1L ? 1.f : 0.f;
  fm0[2] = v0R ? 1.f : 0.f;   fm1[2] = v1R ? 1.f : 0.f;
  fm0[3] = v0U ? 1.f : 0.f;   fm1[3] = v1U ? 1.f : 0.f;
  fm0[4] = v0D ? 1.f : 0.f;   fm1[4] = v1D ? 1.f : 0.f;

  const char* __restrict__ px = (const char*)x;

  f32x4 acc[4][2];   // [ob][a]
  #pragma unroll
  for (int i = 0; i < 4; ++i)
    #pragma unroll
    for (int j = 0; j < 2; ++j)
      acc[i][j] = (f32x4){0.f, 0.f, 0.f, 0.f};

  __syncthreads();   // Wlds ready; last block-wide sync before epilogue

  // ---- main loop: zero barriers; each wave fully independent ----
  #pragma unroll
  for (int ks = 0; ks < 8; ++ks) {
    // x gather (A-operand): channel c = ks*32 + 4j + quad; one basic block.
    float fv0[8], fv1[8];
    #pragma unroll
    for (int j = 0; j < 8; ++j) {
      const int c0 = ks * 32 + 4 * j;           // compile-time after unroll
      unsigned int o0, o1; float m0, m1;
      if (c0 == 48)       { bool hi = quad >= 3;     // straddles c=51
        o0 = hi ? vo0[1] : vo0[0]; o1 = hi ? vo1[1] : vo1[0];
        m0 = hi ? fm0[1] : 1.f;    m1 = hi ? fm1[1] : 1.f; }
      else if (c0 == 100) { bool hi = quad >= 2;     // straddles c=102
        o0 = hi ? vo0[2] : vo0[1]; o1 = hi ? vo1[2] : vo1[1];
        m0 = hi ? fm0[2] : fm0[1]; m1 = hi ? fm1[2] : fm1[1]; }
      else if (c0 == 152) { bool hi = quad >= 1;     // straddles c=153
        o0 = hi ? vo0[3] : vo0[2]; o1 = hi ? vo1[3] : vo1[2];
        m0 = hi ? fm0[3] : fm0[2]; m1 = hi ? fm1[3] : fm1[2]; }
      else {
        const int r = (c0 >= 51) + (c0 >= 102) + (c0 >= 153) + (c0 >= 204);
        o0 = vo0[r]; o1 = vo1[r]; m0 = fm0[r]; m1 = fm1[r];
      }
      const unsigned int cb = (unsigned int)(c0 * HW_) * 4u;
      fv0[j] = *(const float*)(px + (o0 + cb)) * m0;
      fv1[j] = *(const float*)(px + (o1 + cb)) * m1;
    }
    union { short8 v; unsigned int d[4]; } af0, af1;
    #pragma unroll
    for (int jj = 0; jj < 4; ++jj) {
      asm("v_cvt_pk_bf16_f32 %0, %1, %2" : "=v"(af0.d[jj]) : "v"(fv0[2*jj]), "v"(fv0[2*jj+1]));
      asm("v_cvt_pk_bf16_f32 %0, %1, %2" : "=v"(af1.d[jj]) : "v"(fv1[2*jj]), "v"(fv1[2*jj+1]));
    }
    #pragma unroll
    for (int ob = 0; ob < 4; ++ob) {
      const short8 wf = *(const short8*)(&Wlds[((ks * 8 + wo * 4 + ob) * 64 + lane) * 8]);
      acc[ob][0] = __builtin_amdgcn_mfma_f32_16x16x32_bf16(af0.v, wf, acc[ob][0], 0, 0, 0);
      acc[ob][1] = __builtin_amdgcn_mfma_f32_16x16x32_bf16(af1.v, wf, acc[ob][1], 0, 0, 0);
    }
  }

  // ---- epilogue: BN + ReLU, transpose via reused Wlds, coalesced stores ----
  __syncthreads();   // all waves done reading Wlds -> safe to reuse as tbuf
  float invb[4], addb[4];
  #pragma unroll
  for (int b = 0; b < 4; ++b) {
    int ol = wo * 64 + b * 16 + l15;
    invb[b] = bnp[2 * ol];
    addb[b] = bnp[2 * ol + 1];
  }
  float* tb = (float*)&Wlds[0] + wv * 1056;    // 32*33 floats per wave (4224B)
  const int nl  = lane & 31;
  const int ngs = chunk * 128 + wn * 32 + nl;
  const int bis = ngs / HW_;
  const int hws = ngs - bis * HW_;
  const size_t sb = (size_t)bis * COUT_ * HW_ + hws;
  #pragma unroll
  for (int hb = 0; hb < 2; ++hb) {
    #pragma unroll
    for (int bb = 0; bb < 2; ++bb) {
      const int b = hb * 2 + bb;
      #pragma unroll
      for (int a = 0; a < 2; ++a)
        #pragma unroll
        for (int r = 0; r < 4; ++r) {
          float v = fmaxf(fmaf(acc[b][a][r], invb[b], addb[b]), 0.f);
          tb[(bb * 16 + l15) * 33 + (a * 16 + quad * 4 + r)] = v;
        }
    }
    asm volatile("s_waitcnt lgkmcnt(0)" ::: "memory");   // wave-private buffer
    #pragma unroll
    for (int oi = 0; oi < 16; ++oi) {
      int ol  = oi * 2 + (lane >> 5);
      float v = tb[ol * 33 + nl];
      int og  = bm * 128 + wo * 64 + hb * 32 + ol;
      out[sb + (size_t)og * HW_] = v;
    }
    asm volatile("s_waitcnt lgkmcnt(0)" ::: "memory");   // WAR before next half
  }
}

extern "C" void kernel_launch(void* const* d_in, const int* in_sizes, int n_in,
                              void* d_out, int out_size, void* d_ws, size_t ws_size,
                              hipStream_t stream) {
  const float* x     = (const float*)d_in[0];
  const float* wgt   = (const float*)d_in[1];
  const float* gamma = (const float*)d_in[2];
  const float* beta  = (const float*)d_in[3];
  const float* rmean = (const float*)d_in[4];
  const float* rvar  = (const float*)d_in[5];
  float* out = (float*)d_out;

  prep_weights<<<dim3(256), dim3(256), 0, stream>>>(wgt);
  shiftconv_gemm<<<dim3(1568), dim3(512), 0, stream>>>(x, gamma, beta, rmean, rvar, out);
}

// Round 14
// 203.331 us; speedup vs baseline: 1.0420x; 1.0362x over previous
//
#include <hip/hip_runtime.h>

#define H_ 56
#define W_ 56
#define HW_ 3136
#define CIN_ 256
#define COUT_ 256

typedef __attribute__((ext_vector_type(8))) short short8;
typedef __attribute__((ext_vector_type(4))) float f32x4;

// Pre-swizzled bf16 weights, written by prep_weights each launch (idempotent).
// Layout: [kt][e], e = m*32 + col (m 0..255), content =
//   bf16(W[m][kt*32 + (col ^ swz32(m))])
__device__ unsigned short g_wbf[COUT_ * CIN_];

__device__ __forceinline__ int swz32(int n) { return ((n ^ (n >> 3)) & 3) << 3; }

__device__ __forceinline__ unsigned short f2bf(float f) {
  union { float f; unsigned int i; } v; v.f = f;
  unsigned int b = v.i + (0x7fffu + ((v.i >> 16) & 1u));  // RNE
  return (unsigned short)(b >> 16);
}

__device__ __forceinline__ void gload_lds16(const unsigned short* g, unsigned short* l) {
  __builtin_amdgcn_global_load_lds(
      (const __attribute__((address_space(1))) unsigned int*)g,
      (__attribute__((address_space(3))) unsigned int*)l, 16, 0, 0);
}

__device__ __forceinline__ void shift_decode(int c, int& dx, int& dy) {
  if (c < 102)      { dy = 0; dx = (c < 51) ? 0 : 1; }
  else if (c < 153) { dx = -1; dy = 0; }
  else if (c < 204) { dx = 0;  dy = 1; }
  else              { dx = 0;  dy = -1; }
}

__global__ __launch_bounds__(256)
void prep_weights(const float* __restrict__ wgt) {
  int idx = blockIdx.x * 256 + threadIdx.x;   // 0..65535
  int kt  = idx >> 13;                        // 0..7
  int e   = idx & 8191;
  int m   = e >> 5, col = e & 31;             // m 0..255
  int k   = kt * 32 + (col ^ swz32(m));
  g_wbf[idx] = f2bf(wgt[m * CIN_ + k]);
}

// Load next x slice into registers (shift applied later at LDS-write time).
__device__ __forceinline__ void load_x(const float* __restrict__ x, size_t xb,
                                       int hh, int w0, int c,
                                       float4& p0, float4& p1, float& pe) {
  int dx, dy; shift_decode(c, dx, dy);
  int h2 = hh - dy;
  p0 = make_float4(0.f, 0.f, 0.f, 0.f);
  p1 = make_float4(0.f, 0.f, 0.f, 0.f);
  pe = 0.f;
  if ((unsigned)h2 < (unsigned)H_) {
    const float* row = x + xb + (size_t)c * HW_ + h2 * W_;
    p0 = *(const float4*)(row + w0);
    p1 = *(const float4*)(row + w0 + 4);
    if (dx == 1)       { if (w0 > 0)      pe = row[w0 - 1]; }
    else if (dx == -1) { if (w0 + 8 < W_) pe = row[w0 + 8]; }
  }
}

// Apply the W-shift in registers and scatter bf16 into the (transposed) B tile.
__device__ __forceinline__ void write_b(unsigned short* __restrict__ B,
                                        int nloc0, int krow, int c,
                                        const float4& p0, const float4& p1, float pe) {
  int dx, dy; shift_decode(c, dx, dy);
  float s[8] = {p0.x, p0.y, p0.z, p0.w, p1.x, p1.y, p1.z, p1.w};
  float vals[8];
  if (dx == 0) {
    #pragma unroll
    for (int i = 0; i < 8; ++i) vals[i] = s[i];
  } else if (dx == 1) {          // y[w] = x[w-1]
    #pragma unroll
    for (int i = 7; i >= 1; --i) vals[i] = s[i - 1];
    vals[0] = pe;
  } else {                       // dx == -1: y[w] = x[w+1]
    #pragma unroll
    for (int i = 0; i < 7; ++i) vals[i] = s[i + 1];
    vals[7] = pe;
  }
  #pragma unroll
  for (int i = 0; i < 8; ++i) {
    int nl = nloc0 + i;
    B[nl * 32 + (krow ^ swz32(nl))] = f2bf(vals[i]);
  }
}

__global__ __launch_bounds__(256, 3)
void shiftconv_gemm(const float* __restrict__ x,
                    const float* __restrict__ gamma,
                    const float* __restrict__ beta,
                    const float* __restrict__ rmean,
                    const float* __restrict__ rvar,
                    float* __restrict__ out)
{
  // ONLY structural change vs R11 (77.7 us): FULL M=256 per block (was 128),
  // so each x n-slice is staged by exactly ONE block -> x staging work and
  // barrier-tiles halve per dispatch; MFMA per staged B-byte doubles.
  // A [256 m][32 k], B [64 n][32 k], dbuf; layouts/staging verbatim R11.
  __shared__ unsigned short Alds[2][256 * 32];   // 2 x 16 KB
  __shared__ unsigned short Blds[2][64 * 32];    // 2 x 4 KB
  __shared__ float bnp[512];                     // interleaved (inv, add), 256 o

  const int t = threadIdx.x;
  // XCD swizzle: nwg = 1568 = 8*196, bijective chunked mapping (verified).
  const int orig = blockIdx.x;
  const int bn   = (orig & 7) * 196 + (orig >> 3);   // 1568 n-tiles of 64

  const int lane = t & 63;
  const int wv   = t >> 6;
  const int wm   = wv;           // wave o-quarter (64 rows of 256)
  const int quad = lane >> 4;
  const int l15  = lane & 15;

  {
    int o = t;                   // all 256 threads: one BN pair each
    float inv = gamma[o] * rsqrtf(rvar[o] + 1e-5f);
    bnp[2 * t]     = inv;
    bnp[2 * t + 1] = beta[o] - rmean[o] * inv;
  }

  // ---- B staging decode (constant across K loop): 8 n x 1 k per thread ----
  const int chunk  = t & 7;           // 8 chunks of 8 n
  const int krow   = t >> 3;          // 0..31 = k within tile
  const int nloc0  = chunk * 8;
  const int nglob0 = bn * 64 + nloc0;
  const int bidx   = nglob0 / HW_;
  const int rem    = nglob0 - bidx * HW_;
  const int hh     = rem / W_;
  const int w0     = rem - hh * W_;   // multiple of 8
  const size_t xb  = (size_t)bidx * CIN_ * HW_;

  // ---- A staging source: pre-swizzled bf16 weights ----
  const unsigned short* wsrc = g_wbf + t * 8;

  f32x4 acc[4][4];
  #pragma unroll
  for (int i = 0; i < 4; ++i)
    #pragma unroll
    for (int j = 0; j < 4; ++j)
      acc[i][j] = (f32x4){0.f, 0.f, 0.f, 0.f};

  float4 p0, p1;   // raw prefetched x (shift applied at write time)
  float  pe;       // edge element for dx = +/-1

  // ---- prologue: stage tile 0 (A = 16 KB: 4 gload rounds of 4 KB) ----
  {
    const unsigned short* g = wsrc;
    unsigned short* l = &Alds[0][t * 8];
    #pragma unroll
    for (int p = 0; p < 4; ++p)
      gload_lds16(g + p * 2048, l + p * 2048);
  }
  load_x(x, xb, hh, w0, krow, p0, p1, pe);
  write_b(&Blds[0][0], nloc0, krow, krow, p0, p1, pe);
  __syncthreads();

  const int kb = quad * 8;
  int buf = 0;

  // ---- main loop: one barrier per K-tile; next tile's loads in flight ----
  for (int kt = 0; kt < 8; ++kt) {
    if (kt < 7) {
      const unsigned short* g = wsrc + (kt + 1) * 8192;
      unsigned short* l = &Alds[buf ^ 1][t * 8];
      #pragma unroll
      for (int p = 0; p < 4; ++p)
        gload_lds16(g + p * 2048, l + p * 2048);
      load_x(x, xb, hh, w0, (kt + 1) * 32 + krow, p0, p1, pe);
    }

    short8 af[4], bfr[4];
    #pragma unroll
    for (int f = 0; f < 4; ++f) {
      int ml = wm * 64 + f * 16 + l15;
      af[f] = *(const short8*)(&Alds[buf][ml * 32 + (kb ^ swz32(ml))]);
    }
    #pragma unroll
    for (int g2 = 0; g2 < 4; ++g2) {
      int nl2 = g2 * 16 + l15;
      bfr[g2] = *(const short8*)(&Blds[buf][nl2 * 32 + (kb ^ swz32(nl2))]);
    }
    #pragma unroll
    for (int mf = 0; mf < 4; ++mf)
      #pragma unroll
      for (int nf = 0; nf < 4; ++nf)
        acc[mf][nf] = __builtin_amdgcn_mfma_f32_16x16x32_bf16(
            af[mf], bfr[nf], acc[mf][nf], 0, 0, 0);

    if (kt < 7)
      write_b(&Blds[buf ^ 1][0], nloc0, krow, (kt + 1) * 32 + krow, p0, p1, pe);

    __syncthreads();
    buf ^= 1;
  }

  // ---- epilogue: BN + ReLU + fp32 store ----
  size_t nbase[4];
  #pragma unroll
  for (int nf = 0; nf < 4; ++nf) {
    int ng  = bn * 64 + nf * 16 + l15;
    int b2  = ng / HW_;
    int hw2 = ng - b2 * HW_;
    nbase[nf] = (size_t)b2 * COUT_ * HW_ + hw2;
  }
  #pragma unroll
  for (int mf = 0; mf < 4; ++mf) {
    int mloc = wm * 64 + mf * 16 + quad * 4;   // global o for reg r=0
    float inv[4], add[4];
    #pragma unroll
    for (int r = 0; r < 4; ++r) {
      inv[r] = bnp[2 * (mloc + r)];
      add[r] = bnp[2 * (mloc + r) + 1];
    }
    size_t obase = (size_t)mloc * HW_;
    #pragma unroll
    for (int nf = 0; nf < 4; ++nf) {
      #pragma unroll
      for (int r = 0; r < 4; ++r) {
        float v = fmaf(acc[mf][nf][r], inv[r], add[r]);
        out[nbase[nf] + obase + (size_t)r * HW_] = fmaxf(v, 0.0f);
      }
    }
  }
}

extern "C" void kernel_launch(void* const* d_in, const int* in_sizes, int n_in,
                              void* d_out, int out_size, void* d_ws, size_t ws_size,
                              hipStream_t stream) {
  const float* x     = (const float*)d_in[0];
  const float* wgt   = (const float*)d_in[1];
  const float* gamma = (const float*)d_in[2];
  const float* beta  = (const float*)d_in[3];
  const float* rmean = (const float*)d_in[4];
  const float* rvar  = (const float*)d_in[5];
  float* out = (float*)d_out;

  prep_weights<<<dim3(256), dim3(256), 0, stream>>>(wgt);
  shiftconv_gemm<<<dim3(1568), dim3(256), 0, stream>>>(x, gamma, beta, rmean, rvar, out);
}